// Round 2
// baseline (1432.049 us; speedup 1.0000x reference)
//
#include <hip/hip_runtime.h>
#include <math.h>

// GCN 2-layer: out = relu( relu( (A @ x) @ W1 + b1 ) @ W2 + b2 )
// where A = D^-1/2 (Adj + I) D^-1/2  (weighted, self-loops weight 1).
// Key restructure: aggregate at d_in=128 (A@x) then apply W1 — 4x less
// scatter traffic than the reference's A@(x@W1) order. Mathematically equal.

__global__ __launch_bounds__(256) void k_init_deg(float* __restrict__ deg, int n) {
    int i = blockIdx.x * 256 + threadIdx.x;
    if (i < n) deg[i] = 1.0f;  // self-loop weight
}

__global__ __launch_bounds__(256) void k_deg_atomic(const int* __restrict__ dst,
                                                    const float* __restrict__ ew,
                                                    float* __restrict__ deg, int E) {
    int e = blockIdx.x * 256 + threadIdx.x;
    if (e < E) atomicAdd(&deg[dst[e]], ew[e]);
}

__global__ __launch_bounds__(256) void k_dinv(float* __restrict__ deg, int n) {
    int i = blockIdx.x * 256 + threadIdx.x;
    if (i < n) {
        float d = deg[i];
        deg[i] = (d > 0.0f) ? rsqrtf(d) : 0.0f;
    }
}

// y[i] = dinv[i]^2 * x[i]   (self-loop contribution), one float4 per thread
__global__ __launch_bounds__(256) void k_y_init(const float* __restrict__ x,
                                                const float* __restrict__ dinv,
                                                float* __restrict__ y, int n) {
    int idx = blockIdx.x * 256 + threadIdx.x;
    if (idx >= n * 32) return;
    int node = idx >> 5;
    int c4   = idx & 31;
    float di = dinv[node];
    float coef = di * di;
    float4 v = ((const float4*)x)[(size_t)node * 32 + c4];
    float4 o;
    o.x = v.x * coef; o.y = v.y * coef; o.z = v.z * coef; o.w = v.w * coef;
    ((float4*)y)[(size_t)node * 32 + c4] = o;
}

// per-edge scatter: y[dst] += dinv[s]*w*dinv[d] * x[src]; 32 lanes/edge, float4 each
__global__ __launch_bounds__(256) void k_spmm(const int* __restrict__ src,
                                              const int* __restrict__ dst,
                                              const float* __restrict__ ew,
                                              const float* __restrict__ dinv,
                                              const float* __restrict__ x,
                                              float* __restrict__ y, int E) {
    int g = blockIdx.x * 256 + threadIdx.x;
    int e = g >> 5;
    if (e >= E) return;
    int lane = g & 31;
    int s = src[e];
    int d = dst[e];
    float coef = dinv[s] * ew[e] * dinv[d];
    float4 v = ((const float4*)x)[(size_t)s * 32 + lane];
    float* yp = y + (size_t)d * 128 + lane * 4;
    atomicAdd(yp + 0, coef * v.x);
    atomicAdd(yp + 1, coef * v.y);
    atomicAdd(yp + 2, coef * v.z);
    atomicAdd(yp + 3, coef * v.w);
}

// Fused MLP: per block, 32 rows. h = relu(y@W1+b1) staged in LDS, out = relu(h@W2+b2).
// LDS: 16KB (y tile) + 64KB (h tile) = 80KB -> 2 blocks/CU (gfx950 allows >64KB/wg).
__global__ __launch_bounds__(256) void k_mlp(const float* __restrict__ y,
                                             const float* __restrict__ W1,
                                             const float* __restrict__ b1,
                                             const float* __restrict__ W2,
                                             const float* __restrict__ b2,
                                             float* __restrict__ out, int n) {
    __shared__ float ylds[32][128];
    __shared__ float hlds[32][512];
    const int tid  = threadIdx.x;
    const int row0 = blockIdx.x * 32;

    // load y tile (zero-pad rows past n)
#pragma unroll
    for (int i = 0; i < 4; ++i) {
        int idx = tid + i * 256;           // float4 index within tile
        int r  = idx >> 5;                 // 32 float4 per row
        int c4 = idx & 31;
        float4 v = make_float4(0.f, 0.f, 0.f, 0.f);
        if (row0 + r < n) v = ((const float4*)y)[(size_t)(row0 + r) * 32 + c4];
        *(float4*)&ylds[r][c4 * 4] = v;
    }
    __syncthreads();

    // ---- GEMM1: h[32][512] = relu(ylds @ W1 + b1) ----
    {
        const int rg = tid >> 6;           // 0..3  -> 8 rows each
        const int cg = tid & 63;           // 0..63 -> 8 cols each
        const int r0 = rg * 8, c0 = cg * 8;
        float acc[8][8];
#pragma unroll
        for (int r = 0; r < 8; ++r)
#pragma unroll
            for (int c = 0; c < 8; ++c) acc[r][c] = 0.f;

        for (int k = 0; k < 128; k += 4) {
            float a[8][4];
#pragma unroll
            for (int r = 0; r < 8; ++r) {
                float4 t = *(const float4*)&ylds[r0 + r][k];
                a[r][0] = t.x; a[r][1] = t.y; a[r][2] = t.z; a[r][3] = t.w;
            }
            float w[4][8];
#pragma unroll
            for (int kk = 0; kk < 4; ++kk) {
                const float* wp = W1 + (size_t)(k + kk) * 512 + c0;
                float4 t0 = *(const float4*)wp;
                float4 t1 = *(const float4*)(wp + 4);
                w[kk][0] = t0.x; w[kk][1] = t0.y; w[kk][2] = t0.z; w[kk][3] = t0.w;
                w[kk][4] = t1.x; w[kk][5] = t1.y; w[kk][6] = t1.z; w[kk][7] = t1.w;
            }
#pragma unroll
            for (int r = 0; r < 8; ++r)
#pragma unroll
                for (int kk = 0; kk < 4; ++kk)
#pragma unroll
                    for (int c = 0; c < 8; ++c)
                        acc[r][c] = fmaf(a[r][kk], w[kk][c], acc[r][c]);
        }
        float bb[8];
#pragma unroll
        for (int c = 0; c < 8; ++c) bb[c] = b1[c0 + c];
#pragma unroll
        for (int r = 0; r < 8; ++r)
#pragma unroll
            for (int c = 0; c < 8; ++c) {
                float v = acc[r][c] + bb[c];
                hlds[r0 + r][c0 + c] = v > 0.f ? v : 0.f;
            }
    }
    __syncthreads();

    // ---- GEMM2: out[32][128] = relu(hlds @ W2 + b2) ----
    {
        const int rg = tid >> 4;           // 0..15 -> 2 rows each
        const int cg = tid & 15;           // 0..15 -> 8 cols each
        const int r0 = rg * 2, c0 = cg * 8;
        float acc[2][8];
#pragma unroll
        for (int r = 0; r < 2; ++r)
#pragma unroll
            for (int c = 0; c < 8; ++c) acc[r][c] = 0.f;

        for (int k = 0; k < 512; k += 4) {
            float a[2][4];
#pragma unroll
            for (int r = 0; r < 2; ++r) {
                float4 t = *(const float4*)&hlds[r0 + r][k];
                a[r][0] = t.x; a[r][1] = t.y; a[r][2] = t.z; a[r][3] = t.w;
            }
            float w[4][8];
#pragma unroll
            for (int kk = 0; kk < 4; ++kk) {
                const float* wp = W2 + (size_t)(k + kk) * 128 + c0;
                float4 t0 = *(const float4*)wp;
                float4 t1 = *(const float4*)(wp + 4);
                w[kk][0] = t0.x; w[kk][1] = t0.y; w[kk][2] = t0.z; w[kk][3] = t0.w;
                w[kk][4] = t1.x; w[kk][5] = t1.y; w[kk][6] = t1.z; w[kk][7] = t1.w;
            }
#pragma unroll
            for (int r = 0; r < 2; ++r)
#pragma unroll
                for (int kk = 0; kk < 4; ++kk)
#pragma unroll
                    for (int c = 0; c < 8; ++c)
                        acc[r][c] = fmaf(a[r][kk], w[kk][c], acc[r][c]);
        }
        float bb[8];
#pragma unroll
        for (int c = 0; c < 8; ++c) bb[c] = b2[c0 + c];
#pragma unroll
        for (int r = 0; r < 2; ++r) {
            int row = row0 + r0 + r;
            if (row >= n) continue;
            float4 o0, o1;
            o0.x = fmaxf(acc[r][0] + bb[0], 0.f);
            o0.y = fmaxf(acc[r][1] + bb[1], 0.f);
            o0.z = fmaxf(acc[r][2] + bb[2], 0.f);
            o0.w = fmaxf(acc[r][3] + bb[3], 0.f);
            o1.x = fmaxf(acc[r][4] + bb[4], 0.f);
            o1.y = fmaxf(acc[r][5] + bb[5], 0.f);
            o1.z = fmaxf(acc[r][6] + bb[6], 0.f);
            o1.w = fmaxf(acc[r][7] + bb[7], 0.f);
            float* op = out + (size_t)row * 128 + c0;
            *(float4*)op = o0;
            *(float4*)(op + 4) = o1;
        }
    }
}

extern "C" void kernel_launch(void* const* d_in, const int* in_sizes, int n_in,
                              void* d_out, int out_size, void* d_ws, size_t ws_size,
                              hipStream_t stream) {
    const float* x  = (const float*)d_in[0];
    const int*   ei = (const int*)d_in[1];
    const float* ew = (const float*)d_in[2];
    const float* W1 = (const float*)d_in[3];
    const float* b1 = (const float*)d_in[4];
    const float* W2 = (const float*)d_in[5];
    const float* b2 = (const float*)d_in[6];
    float* out = (float*)d_out;

    const int N = in_sizes[0] / 128;
    const int E = in_sizes[2];
    const int* src = ei;
    const int* dst = ei + E;

    float* deg = (float*)d_ws;                       // N floats (becomes dinv in-place)
    float* y   = deg + (((size_t)N + 127) / 128) * 128;  // N*128 floats

    int nb;
    nb = (N + 255) / 256;
    k_init_deg<<<nb, 256, 0, stream>>>(deg, N);
    nb = (E + 255) / 256;
    k_deg_atomic<<<nb, 256, 0, stream>>>(dst, ew, deg, E);
    nb = (N + 255) / 256;
    k_dinv<<<nb, 256, 0, stream>>>(deg, N);
    nb = (N * 32 + 255) / 256;
    k_y_init<<<nb, 256, 0, stream>>>(x, deg, y, N);
    nb = (E * 32 + 255) / 256;  // 32 lanes per edge
    k_spmm<<<nb, 256, 0, stream>>>(src, dst, ew, deg, x, y, E);
    nb = (N + 31) / 32;
    k_mlp<<<nb, 256, 0, stream>>>(y, W1, b1, W2, b2, out, N);
}

// Round 3
// 624.332 us; speedup vs baseline: 2.2937x; 2.2937x over previous
//
#include <hip/hip_runtime.h>
#include <math.h>

// GCN 2-layer: out = relu( relu( (A @ x) @ W1 + b1 ) @ W2 + b2 )
// A = D^-1/2 (Adj + I) D^-1/2 (weighted, self-loop weight 1).
// Aggregation at d_in=128 ((A@x)@W1 == A@(x@W1), linearity).
// R3: replace 76.8M-float-atomic scatter (1010us, 1.2GB atomic write traffic)
// with counting-sort by dst + register-accumulating pull gather (1.8M int atomics).

// init: counts=0, deg=1 (self-loop)
__global__ __launch_bounds__(256) void k_init(int* __restrict__ counts,
                                              float* __restrict__ deg, int n) {
    int i = blockIdx.x * 256 + threadIdx.x;
    if (i < n) { counts[i] = 0; deg[i] = 1.0f; }
}

// histogram of dst + weighted degree
__global__ __launch_bounds__(256) void k_hist(const int* __restrict__ dst,
                                              const float* __restrict__ ew,
                                              int* __restrict__ counts,
                                              float* __restrict__ deg, int E) {
    int e = blockIdx.x * 256 + threadIdx.x;
    if (e < E) {
        int d = dst[e];
        atomicAdd(&counts[d], 1);
        atomicAdd(&deg[d], ew[e]);
    }
}

// single-block exclusive scan: counts -> offsets[0..n], cursor = offsets
__global__ __launch_bounds__(1024) void k_scan(const int* __restrict__ counts,
                                               int* __restrict__ offsets,
                                               int* __restrict__ cursor, int n) {
    __shared__ int partial[1024];
    const int tid = threadIdx.x;
    const int chunk = (n + 1023) / 1024;
    const int begin = tid * chunk;
    const int end = min(begin + chunk, n);
    int sum = 0;
    for (int i = begin; i < end; ++i) sum += counts[i];
    partial[tid] = sum;
    __syncthreads();
    // Hillis-Steele inclusive scan over 1024 partials
    for (int off = 1; off < 1024; off <<= 1) {
        int t = (tid >= off) ? partial[tid - off] : 0;
        __syncthreads();
        partial[tid] += t;
        __syncthreads();
    }
    int run = (tid > 0) ? partial[tid - 1] : 0;  // exclusive base
    for (int i = begin; i < end; ++i) {
        offsets[i] = run;
        cursor[i] = run;
        run += counts[i];
    }
    if (begin < n && end == n) offsets[n] = run;  // total = E
}

__global__ __launch_bounds__(256) void k_dinv(float* __restrict__ deg, int n) {
    int i = blockIdx.x * 256 + threadIdx.x;
    if (i < n) {
        float d = deg[i];
        deg[i] = (d > 0.0f) ? rsqrtf(d) : 0.0f;
    }
}

// scatter edges into dst-sorted slots; precompute edge coefficient
__global__ __launch_bounds__(256) void k_scatter(const int* __restrict__ src,
                                                 const int* __restrict__ dst,
                                                 const float* __restrict__ ew,
                                                 const float* __restrict__ dinv,
                                                 int* __restrict__ cursor,
                                                 int* __restrict__ ssrc,
                                                 float* __restrict__ scoef, int E) {
    int e = blockIdx.x * 256 + threadIdx.x;
    if (e >= E) return;
    int s = src[e];
    int d = dst[e];
    float coef = dinv[s] * ew[e] * dinv[d];
    int pos = atomicAdd(&cursor[d], 1);
    ssrc[pos] = s;
    scoef[pos] = coef;
}

// pull gather: one wave (64 lanes) per node; float2 per lane covers d=128.
// y[i] = dinv[i]^2 * x[i] + sum_j coef_j * x[src_j]
__global__ __launch_bounds__(256) void k_gather(const int* __restrict__ offsets,
                                                const int* __restrict__ ssrc,
                                                const float* __restrict__ scoef,
                                                const float* __restrict__ dinv,
                                                const float* __restrict__ x,
                                                float* __restrict__ y, int n) {
    int wid = (blockIdx.x * 256 + threadIdx.x) >> 6;  // node id
    if (wid >= n) return;
    int lane = threadIdx.x & 63;
    int o0 = offsets[wid];
    int o1 = offsets[wid + 1];
    float di = dinv[wid];
    float2 xv = ((const float2*)x)[(size_t)wid * 64 + lane];
    float2 acc;
    acc.x = di * di * xv.x;
    acc.y = di * di * xv.y;
    for (int j = o0; j < o1; ++j) {
        int s = ssrc[j];          // wave-uniform -> scalar load
        float c = scoef[j];
        float2 v = ((const float2*)x)[(size_t)s * 64 + lane];
        acc.x = fmaf(c, v.x, acc.x);
        acc.y = fmaf(c, v.y, acc.y);
    }
    ((float2*)y)[(size_t)wid * 64 + lane] = acc;
}

// Fused MLP: per block, 32 rows. h = relu(y@W1+b1) staged in LDS, out = relu(h@W2+b2).
// LDS: 16KB (y tile) + 64KB (h tile) = 80KB -> 2 blocks/CU.
__global__ __launch_bounds__(256) void k_mlp(const float* __restrict__ y,
                                             const float* __restrict__ W1,
                                             const float* __restrict__ b1,
                                             const float* __restrict__ W2,
                                             const float* __restrict__ b2,
                                             float* __restrict__ out, int n) {
    __shared__ float ylds[32][128];
    __shared__ float hlds[32][512];
    const int tid  = threadIdx.x;
    const int row0 = blockIdx.x * 32;

#pragma unroll
    for (int i = 0; i < 4; ++i) {
        int idx = tid + i * 256;
        int r  = idx >> 5;
        int c4 = idx & 31;
        float4 v = make_float4(0.f, 0.f, 0.f, 0.f);
        if (row0 + r < n) v = ((const float4*)y)[(size_t)(row0 + r) * 32 + c4];
        *(float4*)&ylds[r][c4 * 4] = v;
    }
    __syncthreads();

    // ---- GEMM1: h[32][512] = relu(ylds @ W1 + b1) ----
    {
        const int rg = tid >> 6;
        const int cg = tid & 63;
        const int r0 = rg * 8, c0 = cg * 8;
        float acc[8][8];
#pragma unroll
        for (int r = 0; r < 8; ++r)
#pragma unroll
            for (int c = 0; c < 8; ++c) acc[r][c] = 0.f;

        for (int k = 0; k < 128; k += 4) {
            float a[8][4];
#pragma unroll
            for (int r = 0; r < 8; ++r) {
                float4 t = *(const float4*)&ylds[r0 + r][k];
                a[r][0] = t.x; a[r][1] = t.y; a[r][2] = t.z; a[r][3] = t.w;
            }
            float w[4][8];
#pragma unroll
            for (int kk = 0; kk < 4; ++kk) {
                const float* wp = W1 + (size_t)(k + kk) * 512 + c0;
                float4 t0 = *(const float4*)wp;
                float4 t1 = *(const float4*)(wp + 4);
                w[kk][0] = t0.x; w[kk][1] = t0.y; w[kk][2] = t0.z; w[kk][3] = t0.w;
                w[kk][4] = t1.x; w[kk][5] = t1.y; w[kk][6] = t1.z; w[kk][7] = t1.w;
            }
#pragma unroll
            for (int r = 0; r < 8; ++r)
#pragma unroll
                for (int kk = 0; kk < 4; ++kk)
#pragma unroll
                    for (int c = 0; c < 8; ++c)
                        acc[r][c] = fmaf(a[r][kk], w[kk][c], acc[r][c]);
        }
        float bb[8];
#pragma unroll
        for (int c = 0; c < 8; ++c) bb[c] = b1[c0 + c];
#pragma unroll
        for (int r = 0; r < 8; ++r)
#pragma unroll
            for (int c = 0; c < 8; ++c) {
                float v = acc[r][c] + bb[c];
                hlds[r0 + r][c0 + c] = v > 0.f ? v : 0.f;
            }
    }
    __syncthreads();

    // ---- GEMM2: out[32][128] = relu(hlds @ W2 + b2) ----
    {
        const int rg = tid >> 4;
        const int cg = tid & 15;
        const int r0 = rg * 2, c0 = cg * 8;
        float acc[2][8];
#pragma unroll
        for (int r = 0; r < 2; ++r)
#pragma unroll
            for (int c = 0; c < 8; ++c) acc[r][c] = 0.f;

        for (int k = 0; k < 512; k += 4) {
            float a[2][4];
#pragma unroll
            for (int r = 0; r < 2; ++r) {
                float4 t = *(const float4*)&hlds[r0 + r][k];
                a[r][0] = t.x; a[r][1] = t.y; a[r][2] = t.z; a[r][3] = t.w;
            }
            float w[4][8];
#pragma unroll
            for (int kk = 0; kk < 4; ++kk) {
                const float* wp = W2 + (size_t)(k + kk) * 128 + c0;
                float4 t0 = *(const float4*)wp;
                float4 t1 = *(const float4*)(wp + 4);
                w[kk][0] = t0.x; w[kk][1] = t0.y; w[kk][2] = t0.z; w[kk][3] = t0.w;
                w[kk][4] = t1.x; w[kk][5] = t1.y; w[kk][6] = t1.z; w[kk][7] = t1.w;
            }
#pragma unroll
            for (int r = 0; r < 2; ++r)
#pragma unroll
                for (int kk = 0; kk < 4; ++kk)
#pragma unroll
                    for (int c = 0; c < 8; ++c)
                        acc[r][c] = fmaf(a[r][kk], w[kk][c], acc[r][c]);
        }
        float bb[8];
#pragma unroll
        for (int c = 0; c < 8; ++c) bb[c] = b2[c0 + c];
#pragma unroll
        for (int r = 0; r < 2; ++r) {
            int row = row0 + r0 + r;
            if (row >= n) continue;
            float4 o0, o1;
            o0.x = fmaxf(acc[r][0] + bb[0], 0.f);
            o0.y = fmaxf(acc[r][1] + bb[1], 0.f);
            o0.z = fmaxf(acc[r][2] + bb[2], 0.f);
            o0.w = fmaxf(acc[r][3] + bb[3], 0.f);
            o1.x = fmaxf(acc[r][4] + bb[4], 0.f);
            o1.y = fmaxf(acc[r][5] + bb[5], 0.f);
            o1.z = fmaxf(acc[r][6] + bb[6], 0.f);
            o1.w = fmaxf(acc[r][7] + bb[7], 0.f);
            float* op = out + (size_t)row * 128 + c0;
            *(float4*)op = o0;
            *(float4*)(op + 4) = o1;
        }
    }
}

extern "C" void kernel_launch(void* const* d_in, const int* in_sizes, int n_in,
                              void* d_out, int out_size, void* d_ws, size_t ws_size,
                              hipStream_t stream) {
    const float* x  = (const float*)d_in[0];
    const int*   ei = (const int*)d_in[1];
    const float* ew = (const float*)d_in[2];
    const float* W1 = (const float*)d_in[3];
    const float* b1 = (const float*)d_in[4];
    const float* W2 = (const float*)d_in[5];
    const float* b2 = (const float*)d_in[6];
    float* out = (float*)d_out;

    const int N = in_sizes[0] / 128;
    const int E = in_sizes[2];
    const int* src = ei;
    const int* dst = ei + E;

    // ws layout (all 4B elems; y first for 16B alignment)
    float* y       = (float*)d_ws;            // N*128
    float* deg     = y + (size_t)N * 128;     // N   (becomes dinv in place)
    int*   counts  = (int*)(deg + N);         // N
    int*   offsets = counts + N;              // N+1
    int*   cursor  = offsets + N + 1;         // N
    int*   ssrc    = cursor + N;              // E
    float* scoef   = (float*)(ssrc + E);      // E

    int nb;
    nb = (N + 255) / 256;
    k_init<<<nb, 256, 0, stream>>>(counts, deg, N);
    nb = (E + 255) / 256;
    k_hist<<<nb, 256, 0, stream>>>(dst, ew, counts, deg, E);
    k_scan<<<1, 1024, 0, stream>>>(counts, offsets, cursor, N);
    nb = (N + 255) / 256;
    k_dinv<<<nb, 256, 0, stream>>>(deg, N);
    nb = (E + 255) / 256;
    k_scatter<<<nb, 256, 0, stream>>>(src, dst, ew, deg, cursor, ssrc, scoef, E);
    nb = (N * 64 + 255) / 256;   // one wave per node
    k_gather<<<nb, 256, 0, stream>>>(offsets, ssrc, scoef, deg, x, y, N);
    nb = (N + 31) / 32;
    k_mlp<<<nb, 256, 0, stream>>>(y, W1, b1, W2, b2, out, N);
}

// Round 4
// 430.576 us; speedup vs baseline: 3.3259x; 1.4500x over previous
//
#include <hip/hip_runtime.h>
#include <math.h>

// GCN 2-layer: out = relu( relu( (A @ x) @ W1 + b1 ) @ W2 + b2 )
// A = D^-1/2 (Adj + I) D^-1/2 (weighted, self-loop weight 1).
// Aggregation at d_in=128 ((A@x)@W1 == A@(x@W1), linearity).
// R4: MLP via mfma_f32_16x16x32_bf16. y split into bf16 hi/lo for layer 1
// (accuracy), weights pre-transposed to [N][K] bf16 so B-frags are
// contiguous-K 16B L2 loads. h staged in XOR-swizzled bf16 LDS.

typedef __attribute__((ext_vector_type(8))) short short8v;   // 8 bf16 = 4 VGPR
typedef __attribute__((ext_vector_type(4))) float floatx4;   // MFMA C/D

__device__ __forceinline__ short f2bf(float f) {             // RNE f32->bf16
    unsigned u = __builtin_bit_cast(unsigned, f);
    unsigned r = (u + 0x7FFFu + ((u >> 16) & 1u)) >> 16;
    return (short)r;
}
__device__ __forceinline__ float bf2f(short s) {
    return __builtin_bit_cast(float, ((unsigned)(unsigned short)s) << 16);
}

// ---------------- graph prologue (unchanged from R3) ----------------

__global__ __launch_bounds__(256) void k_init(int* __restrict__ counts,
                                              float* __restrict__ deg, int n) {
    int i = blockIdx.x * 256 + threadIdx.x;
    if (i < n) { counts[i] = 0; deg[i] = 1.0f; }
}

__global__ __launch_bounds__(256) void k_hist(const int* __restrict__ dst,
                                              const float* __restrict__ ew,
                                              int* __restrict__ counts,
                                              float* __restrict__ deg, int E) {
    int e = blockIdx.x * 256 + threadIdx.x;
    if (e < E) {
        int d = dst[e];
        atomicAdd(&counts[d], 1);
        atomicAdd(&deg[d], ew[e]);
    }
}

__global__ __launch_bounds__(1024) void k_scan(const int* __restrict__ counts,
                                               int* __restrict__ offsets,
                                               int* __restrict__ cursor, int n) {
    __shared__ int partial[1024];
    const int tid = threadIdx.x;
    const int chunk = (n + 1023) / 1024;
    const int begin = tid * chunk;
    const int end = min(begin + chunk, n);
    int sum = 0;
    for (int i = begin; i < end; ++i) sum += counts[i];
    partial[tid] = sum;
    __syncthreads();
    for (int off = 1; off < 1024; off <<= 1) {
        int t = (tid >= off) ? partial[tid - off] : 0;
        __syncthreads();
        partial[tid] += t;
        __syncthreads();
    }
    int run = (tid > 0) ? partial[tid - 1] : 0;
    for (int i = begin; i < end; ++i) {
        offsets[i] = run;
        cursor[i] = run;
        run += counts[i];
    }
    if (begin < n && end == n) offsets[n] = run;
}

__global__ __launch_bounds__(256) void k_dinv(float* __restrict__ deg, int n) {
    int i = blockIdx.x * 256 + threadIdx.x;
    if (i < n) {
        float d = deg[i];
        deg[i] = (d > 0.0f) ? rsqrtf(d) : 0.0f;
    }
}

__global__ __launch_bounds__(256) void k_scatter(const int* __restrict__ src,
                                                 const int* __restrict__ dst,
                                                 const float* __restrict__ ew,
                                                 const float* __restrict__ dinv,
                                                 int* __restrict__ cursor,
                                                 int* __restrict__ ssrc,
                                                 float* __restrict__ scoef, int E) {
    int e = blockIdx.x * 256 + threadIdx.x;
    if (e >= E) return;
    int s = src[e];
    int d = dst[e];
    float coef = dinv[s] * ew[e] * dinv[d];
    int pos = atomicAdd(&cursor[d], 1);
    ssrc[pos] = s;
    scoef[pos] = coef;
}

__global__ __launch_bounds__(256) void k_gather(const int* __restrict__ offsets,
                                                const int* __restrict__ ssrc,
                                                const float* __restrict__ scoef,
                                                const float* __restrict__ dinv,
                                                const float* __restrict__ x,
                                                float* __restrict__ y, int n) {
    int wid = (blockIdx.x * 256 + threadIdx.x) >> 6;
    if (wid >= n) return;
    int lane = threadIdx.x & 63;
    int o0 = offsets[wid];
    int o1 = offsets[wid + 1];
    float di = dinv[wid];
    float2 xv = ((const float2*)x)[(size_t)wid * 64 + lane];
    float2 acc;
    acc.x = di * di * xv.x;
    acc.y = di * di * xv.y;
    for (int j = o0; j < o1; ++j) {
        int s = ssrc[j];
        float c = scoef[j];
        float2 v = ((const float2*)x)[(size_t)s * 64 + lane];
        acc.x = fmaf(c, v.x, acc.x);
        acc.y = fmaf(c, v.y, acc.y);
    }
    ((float2*)y)[(size_t)wid * 64 + lane] = acc;
}

// ---------------- weight prep: transpose + bf16 convert ----------------
// W1t[c][k] = bf16(W1[k][c])  (512 x 128);  W2t[c][k] = bf16(W2[k][c])  (128 x 512)
__global__ __launch_bounds__(256) void k_wprep(const float* __restrict__ W1,
                                               const float* __restrict__ W2,
                                               short* __restrict__ W1t,
                                               short* __restrict__ W2t) {
    int i = blockIdx.x * 256 + threadIdx.x;
    if (i < 65536) {
        int c = i >> 7, k = i & 127;
        W1t[i] = f2bf(W1[k * 512 + c]);
    } else if (i < 131072) {
        int j = i - 65536;
        int c = j >> 9, k = j & 511;
        W2t[j] = f2bf(W2[k * 128 + c]);
    }
}

// ---------------- fused MFMA MLP ----------------
// 32 rows/block, 4 waves. GEMM1: wave w -> h cols [w*128, +128), y hi/lo split.
// GEMM2: wave w -> out cols [w*32, +32). h in swizzled bf16 LDS (32KB).
__global__ __launch_bounds__(256) void k_mlp(const float* __restrict__ y,
                                             const short* __restrict__ W1t,
                                             const float* __restrict__ b1,
                                             const short* __restrict__ W2t,
                                             const float* __restrict__ b2,
                                             float* __restrict__ out, int n) {
    __shared__ __align__(16) short hlds[32 * 512];
    const int tid  = threadIdx.x;
    const int wave = tid >> 6;
    const int lane = tid & 63;
    const int l15  = lane & 15;
    const int lg   = lane >> 4;      // 0..3
    const int row0 = blockIdx.x * 32;

    // ---- GEMM1: h[32][512] = relu(y @ W1 + b1), this wave: cols cb1..cb1+127
    const int cb1 = wave * 128;
    floatx4 acc[2][8];
#pragma unroll
    for (int m = 0; m < 2; ++m)
#pragma unroll
        for (int nn = 0; nn < 8; ++nn) acc[m][nn] = (floatx4)0.0f;

#pragma unroll
    for (int kk = 0; kk < 4; ++kk) {
        const int k0 = kk * 32 + lg * 8;
        short8v bf[8];
#pragma unroll
        for (int nn = 0; nn < 8; ++nn)
            bf[nn] = *(const short8v*)(W1t + (size_t)(cb1 + nn * 16 + l15) * 128 + k0);
#pragma unroll
        for (int m = 0; m < 2; ++m) {
            const float* ap = y + (size_t)(row0 + m * 16 + l15) * 128 + k0;
            float4 f0 = *(const float4*)ap;
            float4 f1 = *(const float4*)(ap + 4);
            float fv[8] = {f0.x, f0.y, f0.z, f0.w, f1.x, f1.y, f1.z, f1.w};
            short8v ahi, alo;
#pragma unroll
            for (int i = 0; i < 8; ++i) {
                short h = f2bf(fv[i]);
                ahi[i] = h;
                alo[i] = f2bf(fv[i] - bf2f(h));   // residual -> ~f32 accuracy on y
            }
#pragma unroll
            for (int nn = 0; nn < 8; ++nn)
                acc[m][nn] = __builtin_amdgcn_mfma_f32_16x16x32_bf16(ahi, bf[nn], acc[m][nn], 0, 0, 0);
#pragma unroll
            for (int nn = 0; nn < 8; ++nn)
                acc[m][nn] = __builtin_amdgcn_mfma_f32_16x16x32_bf16(alo, bf[nn], acc[m][nn], 0, 0, 0);
        }
    }

    // epilogue: bias + relu + bf16, swizzled LDS write
    // D layout: row = m*16 + lg*4 + i, col = l15 (+16*nn) [m89-verified]
#pragma unroll
    for (int m = 0; m < 2; ++m)
#pragma unroll
        for (int nn = 0; nn < 8; ++nn) {
            const int c = cb1 + nn * 16 + l15;
            const float bb = b1[c];
#pragma unroll
            for (int i = 0; i < 4; ++i) {
                const int r = m * 16 + lg * 4 + i;
                float v = acc[m][nn][i] + bb;
                v = v > 0.f ? v : 0.f;
                hlds[r * 512 + (c ^ ((r & 7) << 3))] = f2bf(v);
            }
        }
    __syncthreads();

    // ---- GEMM2: out[32][128] = relu(h @ W2 + b2), this wave: cols cb2..cb2+31
    const int cb2 = wave * 32;
    floatx4 acc2[2][2];
#pragma unroll
    for (int m = 0; m < 2; ++m)
#pragma unroll
        for (int nn = 0; nn < 2; ++nn) acc2[m][nn] = (floatx4)0.0f;

#pragma unroll
    for (int kk = 0; kk < 16; ++kk) {
        const int k0 = kk * 32 + lg * 8;
        short8v bf2[2];
#pragma unroll
        for (int nn = 0; nn < 2; ++nn)
            bf2[nn] = *(const short8v*)(W2t + (size_t)(cb2 + nn * 16 + l15) * 512 + k0);
#pragma unroll
        for (int m = 0; m < 2; ++m) {
            const int r = m * 16 + l15;
            short8v a = *(const short8v*)&hlds[r * 512 + (k0 ^ ((r & 7) << 3))];
#pragma unroll
            for (int nn = 0; nn < 2; ++nn)
                acc2[m][nn] = __builtin_amdgcn_mfma_f32_16x16x32_bf16(a, bf2[nn], acc2[m][nn], 0, 0, 0);
        }
    }

#pragma unroll
    for (int m = 0; m < 2; ++m)
#pragma unroll
        for (int nn = 0; nn < 2; ++nn) {
            const int c = cb2 + nn * 16 + l15;
            const float bb = b2[c];
#pragma unroll
            for (int i = 0; i < 4; ++i) {
                const int rg = row0 + m * 16 + lg * 4 + i;
                if (rg < n) {
                    float v = acc2[m][nn][i] + bb;
                    out[(size_t)rg * 128 + c] = v > 0.f ? v : 0.f;
                }
            }
        }
}

extern "C" void kernel_launch(void* const* d_in, const int* in_sizes, int n_in,
                              void* d_out, int out_size, void* d_ws, size_t ws_size,
                              hipStream_t stream) {
    const float* x  = (const float*)d_in[0];
    const int*   ei = (const int*)d_in[1];
    const float* ew = (const float*)d_in[2];
    const float* W1 = (const float*)d_in[3];
    const float* b1 = (const float*)d_in[4];
    const float* W2 = (const float*)d_in[5];
    const float* b2 = (const float*)d_in[6];
    float* out = (float*)d_out;

    const int N = in_sizes[0] / 128;
    const int E = in_sizes[2];
    const int* src = ei;
    const int* dst = ei + E;

    // ws layout
    float* y       = (float*)d_ws;            // N*128
    float* deg     = y + (size_t)N * 128;     // N (becomes dinv)
    int*   counts  = (int*)(deg + N);         // N
    int*   offsets = counts + N;              // N+1
    int*   cursor  = offsets + N + 1;         // N
    int*   ssrc    = cursor + N;              // E
    float* scoef   = (float*)(ssrc + E);      // E
    short* W1t     = (short*)((((uintptr_t)(scoef + E)) + 15) & ~(uintptr_t)15); // 65536 bf16
    short* W2t     = W1t + 65536;             // 65536 bf16

    int nb;
    k_wprep<<<512, 256, 0, stream>>>(W1, W2, W1t, W2t);
    nb = (N + 255) / 256;
    k_init<<<nb, 256, 0, stream>>>(counts, deg, N);
    nb = (E + 255) / 256;
    k_hist<<<nb, 256, 0, stream>>>(dst, ew, counts, deg, E);
    k_scan<<<1, 1024, 0, stream>>>(counts, offsets, cursor, N);
    nb = (N + 255) / 256;
    k_dinv<<<nb, 256, 0, stream>>>(deg, N);
    nb = (E + 255) / 256;
    k_scatter<<<nb, 256, 0, stream>>>(src, dst, ew, deg, cursor, ssrc, scoef, E);
    nb = (N * 64 + 255) / 256;
    k_gather<<<nb, 256, 0, stream>>>(offsets, ssrc, scoef, deg, x, y, N);
    nb = (N + 31) / 32;
    k_mlp<<<nb, 256, 0, stream>>>(y, W1t, b1, W2t, b2, out, N);
}

// Round 5
// 303.942 us; speedup vs baseline: 4.7116x; 1.4166x over previous
//
#include <hip/hip_runtime.h>
#include <math.h>

// GCN 2-layer: out = relu( relu( (A @ x) @ W1 + b1 ) @ W2 + b2 )
// A = D^-1/2 (Adj + I) D^-1/2 (weighted, self-loop weight 1).
// Aggregation at d_in=128 ((A@x)@W1 == A@(x@W1), linearity).
// R5: replace 111us single-block scan with 3-phase parallel block scan
// (dinv fused into phase A); gather: int2-fused edge data + 4x unrolled
// independent loads to break the dependent-latency chain.

typedef __attribute__((ext_vector_type(8))) short short8v;   // 8 bf16 = 4 VGPR
typedef __attribute__((ext_vector_type(4))) float floatx4;   // MFMA C/D

__device__ __forceinline__ short f2bf(float f) {             // RNE f32->bf16
    unsigned u = __builtin_bit_cast(unsigned, f);
    unsigned r = (u + 0x7FFFu + ((u >> 16) & 1u)) >> 16;
    return (short)r;
}
__device__ __forceinline__ float bf2f(short s) {
    return __builtin_bit_cast(float, ((unsigned)(unsigned short)s) << 16);
}

// ---------------- graph prologue ----------------

__global__ __launch_bounds__(256) void k_init(int* __restrict__ counts,
                                              float* __restrict__ deg, int n) {
    int i = blockIdx.x * 256 + threadIdx.x;
    if (i < n) { counts[i] = 0; deg[i] = 1.0f; }
}

__global__ __launch_bounds__(256) void k_hist(const int* __restrict__ dst,
                                              const float* __restrict__ ew,
                                              int* __restrict__ counts,
                                              float* __restrict__ deg, int E) {
    int e = blockIdx.x * 256 + threadIdx.x;
    if (e < E) {
        int d = dst[e];
        atomicAdd(&counts[d], 1);
        atomicAdd(&deg[d], ew[e]);
    }
}

// Phase A: per-block (256 elems) exclusive scan into offsets, block sums out.
// Fused: deg -> dinv in place.
__global__ __launch_bounds__(256) void k_scanA(const int* __restrict__ counts,
                                               int* __restrict__ offsets,
                                               int* __restrict__ blockSum,
                                               float* __restrict__ deg, int n) {
    __shared__ int sdata[256];
    const int tid = threadIdx.x;
    const int i = blockIdx.x * 256 + tid;
    int c = (i < n) ? counts[i] : 0;
    sdata[tid] = c;
    __syncthreads();
#pragma unroll
    for (int off = 1; off < 256; off <<= 1) {
        int t = (tid >= off) ? sdata[tid - off] : 0;
        __syncthreads();
        sdata[tid] += t;
        __syncthreads();
    }
    if (i < n) offsets[i] = sdata[tid] - c;           // local exclusive prefix
    if (tid == 255) blockSum[blockIdx.x] = sdata[255];
    if (i < n) {
        float d = deg[i];
        deg[i] = (d > 0.f) ? rsqrtf(d) : 0.f;          // deg becomes dinv
    }
}

// Phase B: exclusive scan of <=256 block sums, in place. (NB=196 for N=50000)
__global__ __launch_bounds__(256) void k_scanB(int* __restrict__ blockSum, int nb) {
    __shared__ int sdata[256];
    const int tid = threadIdx.x;
    int v = (tid < nb) ? blockSum[tid] : 0;
    sdata[tid] = v;
    __syncthreads();
#pragma unroll
    for (int off = 1; off < 256; off <<= 1) {
        int t = (tid >= off) ? sdata[tid - off] : 0;
        __syncthreads();
        sdata[tid] += t;
        __syncthreads();
    }
    if (tid < nb) blockSum[tid] = sdata[tid] - v;
}

// Phase C: add block prefix; init cursor; offsets[n] = E.
__global__ __launch_bounds__(256) void k_scanC(int* __restrict__ offsets,
                                               const int* __restrict__ blockSum,
                                               int* __restrict__ cursor, int n, int E) {
    const int i = blockIdx.x * 256 + threadIdx.x;
    if (i < n) {
        int o = offsets[i] + blockSum[blockIdx.x];
        offsets[i] = o;
        cursor[i] = o;
    }
    if (i == 0) offsets[n] = E;
}

// scatter edges into dst-sorted slots; edge payload fused as {src, coef}
__global__ __launch_bounds__(256) void k_scatter(const int* __restrict__ src,
                                                 const int* __restrict__ dst,
                                                 const float* __restrict__ ew,
                                                 const float* __restrict__ dinv,
                                                 int* __restrict__ cursor,
                                                 int2* __restrict__ sedge, int E) {
    int e = blockIdx.x * 256 + threadIdx.x;
    if (e >= E) return;
    int s = src[e];
    int d = dst[e];
    float coef = dinv[s] * ew[e] * dinv[d];
    int pos = atomicAdd(&cursor[d], 1);
    sedge[pos] = make_int2(s, __builtin_bit_cast(int, coef));
}

// pull gather: one wave per node; 4x-unrolled independent edge loads.
__global__ __launch_bounds__(256) void k_gather(const int* __restrict__ offsets,
                                                const int2* __restrict__ sedge,
                                                const float* __restrict__ dinv,
                                                const float* __restrict__ x,
                                                float* __restrict__ y, int n) {
    int wid = (blockIdx.x * 256 + threadIdx.x) >> 6;
    if (wid >= n) return;
    int lane = threadIdx.x & 63;
    int o0 = offsets[wid];
    int o1 = offsets[wid + 1];
    float di = dinv[wid];
    const float2* x2 = (const float2*)x;
    float2 xv = x2[(size_t)wid * 64 + lane];
    float2 acc;
    acc.x = di * di * xv.x;
    acc.y = di * di * xv.y;
    int j = o0;
    for (; j + 4 <= o1; j += 4) {
        int2 e0 = sedge[j], e1 = sedge[j + 1], e2 = sedge[j + 2], e3 = sedge[j + 3];
        float2 v0 = x2[(size_t)e0.x * 64 + lane];
        float2 v1 = x2[(size_t)e1.x * 64 + lane];
        float2 v2 = x2[(size_t)e2.x * 64 + lane];
        float2 v3 = x2[(size_t)e3.x * 64 + lane];
        float c0 = __builtin_bit_cast(float, e0.y);
        float c1 = __builtin_bit_cast(float, e1.y);
        float c2 = __builtin_bit_cast(float, e2.y);
        float c3 = __builtin_bit_cast(float, e3.y);
        acc.x = fmaf(c0, v0.x, acc.x); acc.y = fmaf(c0, v0.y, acc.y);
        acc.x = fmaf(c1, v1.x, acc.x); acc.y = fmaf(c1, v1.y, acc.y);
        acc.x = fmaf(c2, v2.x, acc.x); acc.y = fmaf(c2, v2.y, acc.y);
        acc.x = fmaf(c3, v3.x, acc.x); acc.y = fmaf(c3, v3.y, acc.y);
    }
    for (; j < o1; ++j) {
        int2 e = sedge[j];
        float2 v = x2[(size_t)e.x * 64 + lane];
        float c = __builtin_bit_cast(float, e.y);
        acc.x = fmaf(c, v.x, acc.x);
        acc.y = fmaf(c, v.y, acc.y);
    }
    ((float2*)y)[(size_t)wid * 64 + lane] = acc;
}

// ---------------- weight prep: transpose + bf16 convert ----------------
__global__ __launch_bounds__(256) void k_wprep(const float* __restrict__ W1,
                                               const float* __restrict__ W2,
                                               short* __restrict__ W1t,
                                               short* __restrict__ W2t) {
    int i = blockIdx.x * 256 + threadIdx.x;
    if (i < 65536) {
        int c = i >> 7, k = i & 127;
        W1t[i] = f2bf(W1[k * 512 + c]);
    } else if (i < 131072) {
        int j = i - 65536;
        int c = j >> 9, k = j & 511;
        W2t[j] = f2bf(W2[k * 128 + c]);
    }
}

// ---------------- fused MFMA MLP (unchanged from R4) ----------------
__global__ __launch_bounds__(256) void k_mlp(const float* __restrict__ y,
                                             const short* __restrict__ W1t,
                                             const float* __restrict__ b1,
                                             const short* __restrict__ W2t,
                                             const float* __restrict__ b2,
                                             float* __restrict__ out, int n) {
    __shared__ __align__(16) short hlds[32 * 512];
    const int tid  = threadIdx.x;
    const int wave = tid >> 6;
    const int lane = tid & 63;
    const int l15  = lane & 15;
    const int lg   = lane >> 4;
    const int row0 = blockIdx.x * 32;

    const int cb1 = wave * 128;
    floatx4 acc[2][8];
#pragma unroll
    for (int m = 0; m < 2; ++m)
#pragma unroll
        for (int nn = 0; nn < 8; ++nn) acc[m][nn] = (floatx4)0.0f;

#pragma unroll
    for (int kk = 0; kk < 4; ++kk) {
        const int k0 = kk * 32 + lg * 8;
        short8v bf[8];
#pragma unroll
        for (int nn = 0; nn < 8; ++nn)
            bf[nn] = *(const short8v*)(W1t + (size_t)(cb1 + nn * 16 + l15) * 128 + k0);
#pragma unroll
        for (int m = 0; m < 2; ++m) {
            const float* ap = y + (size_t)(row0 + m * 16 + l15) * 128 + k0;
            float4 f0 = *(const float4*)ap;
            float4 f1 = *(const float4*)(ap + 4);
            float fv[8] = {f0.x, f0.y, f0.z, f0.w, f1.x, f1.y, f1.z, f1.w};
            short8v ahi, alo;
#pragma unroll
            for (int i = 0; i < 8; ++i) {
                short h = f2bf(fv[i]);
                ahi[i] = h;
                alo[i] = f2bf(fv[i] - bf2f(h));
            }
#pragma unroll
            for (int nn = 0; nn < 8; ++nn)
                acc[m][nn] = __builtin_amdgcn_mfma_f32_16x16x32_bf16(ahi, bf[nn], acc[m][nn], 0, 0, 0);
#pragma unroll
            for (int nn = 0; nn < 8; ++nn)
                acc[m][nn] = __builtin_amdgcn_mfma_f32_16x16x32_bf16(alo, bf[nn], acc[m][nn], 0, 0, 0);
        }
    }

#pragma unroll
    for (int m = 0; m < 2; ++m)
#pragma unroll
        for (int nn = 0; nn < 8; ++nn) {
            const int c = cb1 + nn * 16 + l15;
            const float bb = b1[c];
#pragma unroll
            for (int i = 0; i < 4; ++i) {
                const int r = m * 16 + lg * 4 + i;
                float v = acc[m][nn][i] + bb;
                v = v > 0.f ? v : 0.f;
                hlds[r * 512 + (c ^ ((r & 7) << 3))] = f2bf(v);
            }
        }
    __syncthreads();

    const int cb2 = wave * 32;
    floatx4 acc2[2][2];
#pragma unroll
    for (int m = 0; m < 2; ++m)
#pragma unroll
        for (int nn = 0; nn < 2; ++nn) acc2[m][nn] = (floatx4)0.0f;

#pragma unroll
    for (int kk = 0; kk < 16; ++kk) {
        const int k0 = kk * 32 + lg * 8;
        short8v bf2[2];
#pragma unroll
        for (int nn = 0; nn < 2; ++nn)
            bf2[nn] = *(const short8v*)(W2t + (size_t)(cb2 + nn * 16 + l15) * 512 + k0);
#pragma unroll
        for (int m = 0; m < 2; ++m) {
            const int r = m * 16 + l15;
            short8v a = *(const short8v*)&hlds[r * 512 + (k0 ^ ((r & 7) << 3))];
#pragma unroll
            for (int nn = 0; nn < 2; ++nn)
                acc2[m][nn] = __builtin_amdgcn_mfma_f32_16x16x32_bf16(a, bf2[nn], acc2[m][nn], 0, 0, 0);
        }
    }

#pragma unroll
    for (int m = 0; m < 2; ++m)
#pragma unroll
        for (int nn = 0; nn < 2; ++nn) {
            const int c = cb2 + nn * 16 + l15;
            const float bb = b2[c];
#pragma unroll
            for (int i = 0; i < 4; ++i) {
                const int rg = row0 + m * 16 + lg * 4 + i;
                if (rg < n) {
                    float v = acc2[m][nn][i] + bb;
                    out[(size_t)rg * 128 + c] = v > 0.f ? v : 0.f;
                }
            }
        }
}

extern "C" void kernel_launch(void* const* d_in, const int* in_sizes, int n_in,
                              void* d_out, int out_size, void* d_ws, size_t ws_size,
                              hipStream_t stream) {
    const float* x  = (const float*)d_in[0];
    const int*   ei = (const int*)d_in[1];
    const float* ew = (const float*)d_in[2];
    const float* W1 = (const float*)d_in[3];
    const float* b1 = (const float*)d_in[4];
    const float* W2 = (const float*)d_in[5];
    const float* b2 = (const float*)d_in[6];
    float* out = (float*)d_out;

    const int N = in_sizes[0] / 128;
    const int E = in_sizes[2];
    const int* src = ei;
    const int* dst = ei + E;
    const int NB = (N + 255) / 256;   // 196 for N=50000; k_scanB handles <=256

    // ws layout
    float* y        = (float*)d_ws;            // N*128
    float* deg      = y + (size_t)N * 128;     // N (becomes dinv)
    int*   counts   = (int*)(deg + N);         // N
    int*   offsets  = counts + N;              // N+1
    int*   cursor   = offsets + N + 1;         // N
    int*   blockSum = cursor + N;              // 256
    int2*  sedge    = (int2*)((((uintptr_t)(blockSum + 256)) + 15) & ~(uintptr_t)15); // E
    short* W1t      = (short*)(sedge + E);     // 65536 bf16
    short* W2t      = W1t + 65536;             // 65536 bf16

    int nb;
    k_wprep<<<512, 256, 0, stream>>>(W1, W2, W1t, W2t);
    nb = (N + 255) / 256;
    k_init<<<nb, 256, 0, stream>>>(counts, deg, N);
    nb = (E + 255) / 256;
    k_hist<<<nb, 256, 0, stream>>>(dst, ew, counts, deg, E);
    k_scanA<<<NB, 256, 0, stream>>>(counts, offsets, blockSum, deg, N);
    k_scanB<<<1, 256, 0, stream>>>(blockSum, NB);
    k_scanC<<<NB, 256, 0, stream>>>(offsets, blockSum, cursor, N, E);
    nb = (E + 255) / 256;
    k_scatter<<<nb, 256, 0, stream>>>(src, dst, ew, deg, cursor, sedge, E);
    nb = (N * 64 + 255) / 256;
    k_gather<<<nb, 256, 0, stream>>>(offsets, sedge, deg, x, y, N);
    nb = (N + 31) / 32;
    k_mlp<<<nb, 256, 0, stream>>>(y, W1t, b1, W2t, b2, out, N);
}